// Round 15
// baseline (348.525 us; speedup 1.0000x reference)
//
#include <hip/hip_runtime.h>
#include <hip/hip_bf16.h>
#include <cstdint>

typedef __bf16 bf16x8 __attribute__((ext_vector_type(8)));
typedef __bf16 bf16x4 __attribute__((ext_vector_type(4)));
typedef float  f32x4  __attribute__((ext_vector_type(4)));

#define ND 128
#define HID 128

__device__ __forceinline__ f32x4 mfma_bf16(bf16x8 a, bf16x8 b, f32x4 c) {
  return __builtin_amdgcn_mfma_f32_16x16x32_bf16(a, b, c, 0, 0, 0);
}
__device__ __forceinline__ float fast_sigmoid(float x) {
  return __fdividef(1.f, 1.f + __expf(-x));
}
__device__ __forceinline__ float fast_silu(float x) {
  return __fdividef(x, 1.f + __expf(-x));
}
__device__ __forceinline__ float fast_tanh(float x) {
  float cx = fminf(fmaxf(x, -15.f), 15.f);
  float e = __expf(2.f * cx);
  return __fdividef(e - 1.f, e + 1.f);
}

// LDS-only barrier (r14-proven identical to __syncthreads perf; kept for the
// documented semantics: atomics/prefetch may stay in flight).
__device__ __forceinline__ void bar_lds() {
  asm volatile("s_waitcnt lgkmcnt(0)\n\ts_barrier" ::: "memory");
  __builtin_amdgcn_sched_barrier(0);
}

// ---- prep: cvt 5 segments + zero agg + dst histogram (counts pre-zeroed
// by hipMemsetAsync, stream-ordered before this kernel) ----
__global__ void k_prep(const float* __restrict__ s0, __bf16* __restrict__ d0, int c1,
                       const float* __restrict__ s1, __bf16* __restrict__ d1, int c2,
                       const float* __restrict__ s2, __bf16* __restrict__ d2, int c3,
                       const float* __restrict__ s3, __bf16* __restrict__ d3, int c4,
                       const float* __restrict__ s4, __bf16* __restrict__ d4, int c5,
                       float* __restrict__ agg, int aggz,
                       const int* __restrict__ dst, int* __restrict__ counts, int E) {
  int i = blockIdx.x * blockDim.x + threadIdx.x;
  if (i < c5) {
    const float* s; __bf16* d; int j;
    if (i < c1)      { s = s0; d = d0; j = i; }
    else if (i < c2) { s = s1; d = d1; j = i - c1; }
    else if (i < c3) { s = s2; d = d2; j = i - c2; }
    else if (i < c4) { s = s3; d = d3; j = i - c3; }
    else             { s = s4; d = d4; j = i - c4; }
    const float4* sp = reinterpret_cast<const float4*>(s) + (size_t)j * 2;
    float4 a = sp[0], b = sp[1];
    bf16x8 v;
    v[0] = (__bf16)a.x; v[1] = (__bf16)a.y; v[2] = (__bf16)a.z; v[3] = (__bf16)a.w;
    v[4] = (__bf16)b.x; v[5] = (__bf16)b.y; v[6] = (__bf16)b.z; v[7] = (__bf16)b.w;
    reinterpret_cast<bf16x8*>(d)[j] = v;
    return;
  }
  int k = i - c5;
  if (k < aggz) {
    float4 z = make_float4(0.f, 0.f, 0.f, 0.f);
    float4* p = reinterpret_cast<float4*>(agg) + (size_t)k * 2;
    p[0] = z; p[1] = z;
    return;
  }
  k -= aggz;
  if (k < E) atomicAdd(&counts[dst[k]], 1);
}

// ================= sort machinery =================
__global__ void k_blocksum(const int* __restrict__ counts, int* __restrict__ bsum) {
  __shared__ int sd[256];
  int t = threadIdx.x;
  sd[t] = counts[blockIdx.x * 256 + t];
  __syncthreads();
  for (int d = 128; d > 0; d >>= 1) { if (t < d) sd[t] += sd[t + d]; __syncthreads(); }
  if (!t) bsum[blockIdx.x] = sd[0];
}

// fused: recompute bsum exclusive prefix per block, then scan local counts
__global__ void k_scan_write(const int* __restrict__ counts, const int* __restrict__ bsum,
                             int* __restrict__ cursor, int nb) {
  __shared__ int sd[256];
  int t = threadIdx.x, b = blockIdx.x;
  int v = (t < nb) ? bsum[t] : 0;
  sd[t] = v;
  __syncthreads();
  for (int d = 1; d < 256; d <<= 1) {
    int u = (t >= d) ? sd[t - d] : 0;
    __syncthreads();
    sd[t] += u;
    __syncthreads();
  }
  int bexcl = (b == 0) ? 0 : sd[b - 1];
  __syncthreads();
  int i = b * 256 + t;
  int c = counts[i];
  sd[t] = c;
  __syncthreads();
  for (int d = 1; d < 256; d <<= 1) {
    int u = (t >= d) ? sd[t - d] : 0;
    __syncthreads();
    sd[t] += u;
    __syncthreads();
  }
  cursor[i] = bexcl + sd[t] - c;   // exclusive prefix
}

// one scattered 16B store per edge: {src, dst, e, 0} at sorted position
__global__ void k_perm(const int* __restrict__ src, const int* __restrict__ dst,
                       int* __restrict__ cursor, int4* __restrict__ einfo, int E) {
  int e = blockIdx.x * 256 + threadIdx.x;
  if (e < E) {
    int d = dst[e];
    int p = atomicAdd(&cursor[d], 1);
    einfo[p] = make_int4(src[e], d, e, 0);
  }
}

// ================= fused edge MLP + aggregate (r12/r14 body) =================
// 8 waves, wave w owns j-strip [w*16,w*16+16). A tile [64][320B]: chunks
// 0..15 = x (^ (s&7)), 16..19 = ea (^ (s&3)). H1 [64][256B] ^ (s&7).
// M (layer-2 out) overlays A region as [64][256B] ^ (s&7).
// Flush: waves 0-3, 16-slot groups, b32 col-pairs, readlane segmented scan.
// launch_bounds (512,4) REQUIRED: 64-VGPR cap (r10: 72 VGPR -> occ 42->23%).
#define TILE_E 64

__global__ __launch_bounds__(512, 4) void edge_mlp10(
    const __bf16* __restrict__ xb,
    const float*  __restrict__ ea,       // [E,32] f32
    const __bf16* __restrict__ W1b,      // [128,160]
    const float*  __restrict__ b1,
    const __bf16* __restrict__ W2b,      // [128,128]
    const float*  __restrict__ b2,
    const int4*   __restrict__ einfo,    // [E] slot -> {src,dst,e,0}
    float* __restrict__ agg,             // [N,128] f32, zeroed
    int ntiles)
{
  __shared__ __bf16 Als[TILE_E * 160];   // 20 KB; first 16KB reused as M
  __shared__ __bf16 H1[TILE_E * 128];    // 16 KB
  __shared__ int dstls[TILE_E];
  char* AB = (char*)Als;
  char* HB = (char*)H1;

  const int tid = threadIdx.x;
  const int w  = tid >> 6;
  const int l  = tid & 63;
  const int l4 = l >> 4;
  const int lm = l & 15;
  const int jb = w * 16;

  // weight fragments (A operand): row j = jb+lm, k = kt*32 + l4*8
  bf16x8 bw1[5], bw2[4];
  {
    const int jr = jb + lm;
#pragma unroll
    for (int kt = 0; kt < 5; ++kt)
      bw1[kt] = *reinterpret_cast<const bf16x8*>(W1b + (size_t)jr * 160 + kt * 32 + l4 * 8);
#pragma unroll
    for (int kt = 0; kt < 4; ++kt)
      bw2[kt] = *reinterpret_cast<const bf16x8*>(W2b + (size_t)jr * 128 + kt * 32 + l4 * 8);
  }
  const float4 b1v = *reinterpret_cast<const float4*>(b1 + jb + l4 * 4);
  const float4 b2v = *reinterpret_cast<const float4*>(b2 + jb + l4 * 4);

  // staging thread mapping
  const int xslot = tid >> 4, xq = tid & 15;     // x: 2 chunks (slots xslot, xslot+32)
  const int aslot = tid >> 3, aq = tid & 7;      // ea: 1 float4

  // prefetch registers
  bf16x8 pxv0 = {}, pxv1 = {};
  float4 pea_ = {};
  int pdst_ = 0;

  auto PREFETCH = [&](int t) {
    int p0 = t * TILE_E;
    int s0 = einfo[p0 + xslot].x;
    int s1 = einfo[p0 + xslot + 32].x;
    pxv0 = *reinterpret_cast<const bf16x8*>(xb + (size_t)s0 * ND + xq * 8);
    pxv1 = *reinterpret_cast<const bf16x8*>(xb + (size_t)s1 * ND + xq * 8);
    int e2 = einfo[p0 + aslot].z;
    pea_ = reinterpret_cast<const float4*>(ea)[(size_t)e2 * 8 + aq];
    if (tid < TILE_E) pdst_ = einfo[p0 + tid].y;
  };

  // bijective XCD-chunked swizzle of block id (m204)
  int nwg = gridDim.x;
  int q = nwg >> 3, r = nwg & 7;
  int xcd = blockIdx.x & 7, pos = blockIdx.x >> 3;
  int swz = (xcd < r ? xcd * (q + 1) : r * (q + 1) + (xcd - r) * q) + pos;

  int tile = swz;
  if (tile < ntiles) PREFETCH(tile);

  for (; tile < ntiles; tile += gridDim.x) {
    bar_lds();   // prev flush's LDS reads done

    // ---- write staged regs -> LDS ----
    {
      int s_ = xslot;
      *reinterpret_cast<bf16x8*>(AB + s_ * 320 + ((xq ^ (s_ & 7)) << 4)) = pxv0;
      int s2 = xslot + 32;
      *reinterpret_cast<bf16x8*>(AB + s2 * 320 + ((xq ^ (s2 & 7)) << 4)) = pxv1;
    }
    {
      bf16x4 h;
      h[0] = (__bf16)pea_.x; h[1] = (__bf16)pea_.y;
      h[2] = (__bf16)pea_.z; h[3] = (__bf16)pea_.w;
      int pc = 16 + ((aq >> 1) ^ (aslot & 3));
      *reinterpret_cast<bf16x4*>(AB + aslot * 320 + (pc << 4) + ((aq & 1) << 3)) = h;
    }
    if (tid < TILE_E) dstls[tid] = pdst_;
    bar_lds();   // tile staged

    // ---- prefetch next tile (hidden under both MFMA layers) ----
    int nt = tile + gridDim.x;
    if (nt < ntiles) PREFETCH(nt);

    __builtin_amdgcn_s_setprio(1);
    // ---- layer 1: H1^T[j][slot] = silu(W1 . A^T) ----
#pragma unroll
    for (int et = 0; et < 4; ++et) {
      const int s_ = et * 16 + lm;
      const int sw = s_ & 7;
      f32x4 acc = {0.f, 0.f, 0.f, 0.f};
#pragma unroll
      for (int kt = 0; kt < 4; ++kt) {
        bf16x8 bfrag = *reinterpret_cast<const bf16x8*>(AB + s_ * 320 + (((kt * 4 + l4) ^ sw) << 4));
        acc = mfma_bf16(bw1[kt], bfrag, acc);
      }
      {
        bf16x8 bfrag = *reinterpret_cast<const bf16x8*>(AB + s_ * 320 + ((16 + (l4 ^ (s_ & 3))) << 4));
        acc = mfma_bf16(bw1[4], bfrag, acc);
      }
      bf16x4 h0;
#pragma unroll
      for (int rr = 0; rr < 4; ++rr)
        h0[rr] = (__bf16)fast_silu(acc[rr] + (&b1v.x)[rr]);
      int c0 = w * 2 + (l4 >> 1);
      int inner = (l4 & 1) << 3;
      *reinterpret_cast<bf16x4*>(HB + s_ * 256 + ((c0 ^ sw) << 4) + inner) = h0;
    }
    bar_lds();   // H1 visible

    // ---- layer 2: M^T[j][slot] = silu(W2 . H1^T) -> M tile in A region ----
#pragma unroll
    for (int et = 0; et < 4; ++et) {
      const int s_ = et * 16 + lm;
      const int sw = s_ & 7;
      f32x4 acc = {0.f, 0.f, 0.f, 0.f};
#pragma unroll
      for (int kt = 0; kt < 4; ++kt) {
        bf16x8 bfrag = *reinterpret_cast<const bf16x8*>(HB + s_ * 256 + (((kt * 4 + l4) ^ sw) << 4));
        acc = mfma_bf16(bw2[kt], bfrag, acc);
      }
      bf16x4 m0;
#pragma unroll
      for (int rr = 0; rr < 4; ++rr)
        m0[rr] = (__bf16)fast_silu(acc[rr] + (&b2v.x)[rr]);
      int c0 = w * 2 + (l4 >> 1);
      int inner = (l4 & 1) << 3;
      *reinterpret_cast<bf16x4*>(AB + s_ * 256 + ((c0 ^ sw) << 4) + inner) = m0;
    }
    __builtin_amdgcn_s_setprio(0);
    bar_lds();   // M visible

    // ---- segmented flush: waves 0-3, 16-slot groups, b32 col-pairs ----
    if (w < 4) {
      const int base = w * 16;
      int myd = dstls[base + (l & 15)];
      float a0 = 0.f, a1 = 0.f;
      int cur = __builtin_amdgcn_readlane(myd, 0);
#pragma unroll
      for (int i = 0; i < 16; ++i) {
        int nd = __builtin_amdgcn_readlane(myd, i);
        if (nd != cur) {
          atomicAdd(agg + (size_t)cur * HID + l * 2, a0);
          atomicAdd(agg + (size_t)cur * HID + l * 2 + 1, a1);
          a0 = 0.f; a1 = 0.f; cur = nd;
        }
        int ss = base + i;
        uint32_t u = *reinterpret_cast<const uint32_t*>(
            AB + ss * 256 + (((l >> 2) ^ (ss & 7)) << 4) + ((l & 3) << 2));
        a0 += __uint_as_float(u << 16);
        a1 += __uint_as_float(u & 0xffff0000u);
      }
      atomicAdd(agg + (size_t)cur * HID + l * 2, a0);
      atomicAdd(agg + (size_t)cur * HID + l * 2 + 1, a1);
    }
  }
}

// ================= GRU (weights-as-A, transposed, grid-strided) =============
__global__ __launch_bounds__(512) void gru3(
    const float*  __restrict__ agg,      // [N,128] f32
    const __bf16* __restrict__ xb,
    const float*  __restrict__ x,
    const __bf16* __restrict__ Wih, const float* __restrict__ bih,  // [384,128]
    const __bf16* __restrict__ Whh, const float* __restrict__ bhh,
    float* __restrict__ out, int N, int ntilesN)
{
  const int tid = threadIdx.x;
  const int w = tid >> 6, l = tid & 63;
  const int l4 = l >> 4, lm = l & 15;
  const int jb = w * 16;
  const int jr = jb + lm, jz = jr + 128, jn = jr + 256;

  bf16x8 WiR[4], WhR[4], WiZ[4], WhZ[4], WiN[4], WhN[4];
#pragma unroll
  for (int kt = 0; kt < 4; ++kt) {
    int ko = kt * 32 + l4 * 8;
    WiR[kt] = *reinterpret_cast<const bf16x8*>(Wih + (size_t)jr * ND + ko);
    WhR[kt] = *reinterpret_cast<const bf16x8*>(Whh + (size_t)jr * ND + ko);
    WiZ[kt] = *reinterpret_cast<const bf16x8*>(Wih + (size_t)jz * ND + ko);
    WhZ[kt] = *reinterpret_cast<const bf16x8*>(Whh + (size_t)jz * ND + ko);
    WiN[kt] = *reinterpret_cast<const bf16x8*>(Wih + (size_t)jn * ND + ko);
    WhN[kt] = *reinterpret_cast<const bf16x8*>(Whh + (size_t)jn * ND + ko);
  }
  float4 birv, bizv, binv, bhnv;
  {
    int j0 = jb + l4 * 4;
    float4 a = *reinterpret_cast<const float4*>(bih + j0);
    float4 b = *reinterpret_cast<const float4*>(bhh + j0);
    birv = make_float4(a.x + b.x, a.y + b.y, a.z + b.z, a.w + b.w);
    a = *reinterpret_cast<const float4*>(bih + 128 + j0);
    b = *reinterpret_cast<const float4*>(bhh + 128 + j0);
    bizv = make_float4(a.x + b.x, a.y + b.y, a.z + b.z, a.w + b.w);
    binv = *reinterpret_cast<const float4*>(bih + 256 + j0);
    bhnv = *reinterpret_cast<const float4*>(bhh + 256 + j0);
  }

  for (int bt = blockIdx.x; bt < ntilesN; bt += gridDim.x) {
    const int n0 = bt * 64;
#pragma unroll
    for (int rt = 0; rt < 4; ++rt) {
      const int node = n0 + rt * 16 + lm;
      const bool ok = node < N;
      bf16x8 aA[4], aX[4];
#pragma unroll
      for (int kt = 0; kt < 4; ++kt) {
        int ko = kt * 32 + l4 * 8;
        bf16x8 z8 = {};
        if (ok) {
          float4 a0 = *reinterpret_cast<const float4*>(agg + (size_t)node * ND + ko);
          float4 a1 = *reinterpret_cast<const float4*>(agg + (size_t)node * ND + ko + 4);
          bf16x8 v;
          v[0] = (__bf16)a0.x; v[1] = (__bf16)a0.y; v[2] = (__bf16)a0.z; v[3] = (__bf16)a0.w;
          v[4] = (__bf16)a1.x; v[5] = (__bf16)a1.y; v[6] = (__bf16)a1.z; v[7] = (__bf16)a1.w;
          aA[kt] = v;
          aX[kt] = *reinterpret_cast<const bf16x8*>(xb + (size_t)node * ND + ko);
        } else {
          aA[kt] = z8;
          aX[kt] = z8;
        }
      }
      f32x4 aR = {0.f,0.f,0.f,0.f}, aZ = {0.f,0.f,0.f,0.f};
      f32x4 ai = {0.f,0.f,0.f,0.f}, ah = {0.f,0.f,0.f,0.f};
#pragma unroll
      for (int kt = 0; kt < 4; ++kt) {
        aR = mfma_bf16(WiR[kt], aA[kt], aR);
        aR = mfma_bf16(WhR[kt], aX[kt], aR);
        aZ = mfma_bf16(WiZ[kt], aA[kt], aZ);
        aZ = mfma_bf16(WhZ[kt], aX[kt], aZ);
        ai = mfma_bf16(WiN[kt], aA[kt], ai);
        ah = mfma_bf16(WhN[kt], aX[kt], ah);
      }
      if (ok) {
        float4 xv = *reinterpret_cast<const float4*>(x + (size_t)node * ND + jb + l4 * 4);
        float4 ov;
#pragma unroll
        for (int rr = 0; rr < 4; ++rr) {
          float r = fast_sigmoid(aR[rr] + (&birv.x)[rr]);
          float z = fast_sigmoid(aZ[rr] + (&bizv.x)[rr]);
          float n = fast_tanh(ai[rr] + (&binv.x)[rr] + r * (ah[rr] + (&bhnv.x)[rr]));
          (&ov.x)[rr] = (1.f - z) * n + z * (&xv.x)[rr];
        }
        *reinterpret_cast<float4*>(out + (size_t)node * ND + jb + l4 * 4) = ov;
      }
    }
  }
}

extern "C" void kernel_launch(void* const* d_in, const int* in_sizes, int n_in,
                              void* d_out, int out_size, void* d_ws, size_t ws_size,
                              hipStream_t stream) {
  const float* x   = (const float*)d_in[0];
  const int*   ei  = (const int*)d_in[1];
  const float* ea  = (const float*)d_in[2];
  const float* W1  = (const float*)d_in[3];
  const float* b1  = (const float*)d_in[4];
  const float* W2  = (const float*)d_in[5];
  const float* b2  = (const float*)d_in[6];
  const float* Wih = (const float*)d_in[7];
  const float* bih = (const float*)d_in[8];
  const float* Whh = (const float*)d_in[9];
  const float* bhh = (const float*)d_in[10];
  float* out = (float*)d_out;
  const int N = in_sizes[0] / ND;       // 50000
  const int E = in_sizes[1] / 2;        // 800000

  const int nb = (N + 255) / 256;
  const int nC = nb * 256;

  char* ws = (char*)d_ws;
  size_t off = 0;
  auto alloc = [&](size_t bytes) -> void* {
    void* p = ws + off;
    off += (bytes + 255) & ~(size_t)255;
    return p;
  };
  __bf16* xb      = (__bf16*)alloc((size_t)N * ND * 2);
  __bf16* W1b     = (__bf16*)alloc(128 * 160 * 2);
  __bf16* W2b     = (__bf16*)alloc(128 * 128 * 2);
  __bf16* Wihb    = (__bf16*)alloc(384 * 128 * 2);
  __bf16* Whhb    = (__bf16*)alloc(384 * 128 * 2);
  int*    counts  = (int*)alloc((size_t)nC * 4);
  int*    cursor  = (int*)alloc((size_t)nC * 4);
  int*    bsum    = (int*)alloc(256 * 4);
  int4*   einfo   = (int4*)alloc((size_t)E * 16);
  float*  agg     = (float*)alloc((size_t)N * ND * 4);
  (void)ws_size;

  const int* srcp = ei;
  const int* dstp = ei + E;

  // counts zeroed BEFORE k_prep (stream-ordered) so fused hist atomics are safe
  hipMemsetAsync(counts, 0, (size_t)nC * 4, stream);

  const int n8_x = N * ND / 8, n8_1 = 128 * 160 / 8, n8_2 = 128 * 128 / 8, n8_g = 384 * 128 / 8;
  int c1 = n8_x, c2 = c1 + n8_1, c3 = c2 + n8_2, c4 = c3 + n8_g, c5 = c4 + n8_g;
  int aggz = N * ND / 8;
  int prep_total = c5 + aggz + E;
  k_prep<<<(prep_total + 255) / 256, 256, 0, stream>>>(
      x, xb, c1, W1, W1b, c2, W2, W2b, c3, Wih, Wihb, c4, Whh, Whhb, c5,
      agg, aggz, dstp, counts, E);

  k_blocksum<<<nb, 256, 0, stream>>>(counts, bsum);
  k_scan_write<<<nb, 256, 0, stream>>>(counts, bsum, cursor, nb);
  k_perm<<<(E + 255) / 256, 256, 0, stream>>>(srcp, dstp, cursor, einfo, E);

  const int ntiles = E / TILE_E;   // 12500
  edge_mlp10<<<2048, 512, 0, stream>>>(xb, ea, W1b, b1, W2b, b2,
                                       einfo, agg, ntiles);

  const int ntilesN = (N + 63) / 64;
  gru3<<<256, 512, 0, stream>>>(agg, xb, x, Wihb, bih, Whhb, bhh, out, N, ntilesN);
}

// Round 16
// 324.625 us; speedup vs baseline: 1.0736x; 1.0736x over previous
//
#include <hip/hip_runtime.h>
#include <hip/hip_bf16.h>
#include <cstdint>

typedef __bf16 bf16x8 __attribute__((ext_vector_type(8)));
typedef __bf16 bf16x4 __attribute__((ext_vector_type(4)));
typedef float  f32x4  __attribute__((ext_vector_type(4)));

#define ND 128
#define HID 128

__device__ __forceinline__ f32x4 mfma_bf16(bf16x8 a, bf16x8 b, f32x4 c) {
  return __builtin_amdgcn_mfma_f32_16x16x32_bf16(a, b, c, 0, 0, 0);
}
__device__ __forceinline__ float fast_sigmoid(float x) {
  return __fdividef(1.f, 1.f + __expf(-x));
}
__device__ __forceinline__ float fast_silu(float x) {
  return __fdividef(x, 1.f + __expf(-x));
}
__device__ __forceinline__ float fast_tanh(float x) {
  float cx = fminf(fmaxf(x, -15.f), 15.f);
  float e = __expf(2.f * cx);
  return __fdividef(e - 1.f, e + 1.f);
}

// LDS-only barrier: drains lgkmcnt, leaves vmem (prefetch/atomics) in flight.
__device__ __forceinline__ void bar_lds() {
  asm volatile("s_waitcnt lgkmcnt(0)\n\ts_barrier" ::: "memory");
  __builtin_amdgcn_sched_barrier(0);
}

// pack two f32 into a u32 of 2 bf16 (truncation; r6-proven for biases)
__device__ __forceinline__ unsigned pk2(float a, float b) {
  return (__builtin_bit_cast(unsigned, a) >> 16) |
         (__builtin_bit_cast(unsigned, b) & 0xffff0000u);
}

// ---- prep: zero agg + zero counts + f32->bf16 cvt over 5 segments ----
__global__ void k_prep(const float* __restrict__ s0, __bf16* __restrict__ d0, int c1,
                       const float* __restrict__ s1, __bf16* __restrict__ d1, int c2,
                       const float* __restrict__ s2, __bf16* __restrict__ d2, int c3,
                       const float* __restrict__ s3, __bf16* __restrict__ d3, int c4,
                       const float* __restrict__ s4, __bf16* __restrict__ d4, int c5,
                       float* __restrict__ agg, int aggz,
                       int* __restrict__ counts, int cntz) {
  int i = blockIdx.x * blockDim.x + threadIdx.x;
  if (i < c5) {
    const float* s; __bf16* d; int j;
    if (i < c1)      { s = s0; d = d0; j = i; }
    else if (i < c2) { s = s1; d = d1; j = i - c1; }
    else if (i < c3) { s = s2; d = d2; j = i - c2; }
    else if (i < c4) { s = s3; d = d3; j = i - c3; }
    else             { s = s4; d = d4; j = i - c4; }
    const float4* sp = reinterpret_cast<const float4*>(s) + (size_t)j * 2;
    float4 a = sp[0], b = sp[1];
    bf16x8 v;
    v[0] = (__bf16)a.x; v[1] = (__bf16)a.y; v[2] = (__bf16)a.z; v[3] = (__bf16)a.w;
    v[4] = (__bf16)b.x; v[5] = (__bf16)b.y; v[6] = (__bf16)b.z; v[7] = (__bf16)b.w;
    reinterpret_cast<bf16x8*>(d)[j] = v;
    return;
  }
  int k = i - c5;
  if (k < aggz) {
    float4 z = make_float4(0.f, 0.f, 0.f, 0.f);
    float4* p = reinterpret_cast<float4*>(agg) + (size_t)k * 2;
    p[0] = z; p[1] = z;
    return;
  }
  k -= aggz;
  if (k < cntz) {
    int4 z = make_int4(0, 0, 0, 0);
    int4* p = reinterpret_cast<int4*>(counts) + (size_t)k * 2;
    p[0] = z; p[1] = z;
  }
}

// ================= sort machinery =================
__global__ void k_hist(const int* __restrict__ dst, int* __restrict__ counts, int E) {
  int e = blockIdx.x * 256 + threadIdx.x;
  if (e < E) atomicAdd(&counts[dst[e]], 1);
}

__global__ void k_blocksum(const int* __restrict__ counts, int* __restrict__ bsum) {
  __shared__ int sd[256];
  int t = threadIdx.x;
  sd[t] = counts[blockIdx.x * 256 + t];
  __syncthreads();
  for (int d = 128; d > 0; d >>= 1) { if (t < d) sd[t] += sd[t + d]; __syncthreads(); }
  if (!t) bsum[blockIdx.x] = sd[0];
}

// fused: recompute bsum exclusive prefix per block, then scan local counts
__global__ void k_scan_write(const int* __restrict__ counts, const int* __restrict__ bsum,
                             int* __restrict__ cursor, int nb) {
  __shared__ int sd[256];
  int t = threadIdx.x, b = blockIdx.x;
  int v = (t < nb) ? bsum[t] : 0;
  sd[t] = v;
  __syncthreads();
  for (int d = 1; d < 256; d <<= 1) {
    int u = (t >= d) ? sd[t - d] : 0;
    __syncthreads();
    sd[t] += u;
    __syncthreads();
  }
  int bexcl = (b == 0) ? 0 : sd[b - 1];
  __syncthreads();
  int i = b * 256 + t;
  int c = counts[i];
  sd[t] = c;
  __syncthreads();
  for (int d = 1; d < 256; d <<= 1) {
    int u = (t >= d) ? sd[t - d] : 0;
    __syncthreads();
    sd[t] += u;
    __syncthreads();
  }
  cursor[i] = bexcl + sd[t] - c;   // exclusive prefix
}

// one scattered 16B store per edge: {src, dst, e, 0} at sorted position
__global__ void k_perm(const int* __restrict__ src, const int* __restrict__ dst,
                       int* __restrict__ cursor, int4* __restrict__ einfo, int E) {
  int e = blockIdx.x * 256 + threadIdx.x;
  if (e < E) {
    int d = dst[e];
    int p = atomicAdd(&cursor[d], 1);
    einfo[p] = make_int4(src[e], d, e, 0);
  }
}

// ================= fused edge MLP + aggregate (split prefetch) ===============
// r12/r14 body. NEW: two-stage prefetch -- PREFETCH_IDX (einfo gathers) right
// after staging barrier, PREFETCH_DATA (dependent x/ea gathers) after L1 phase
// (einfo latency hides under L1 MFMA; data latency under L2+flush).
// Biases packed to bf16 pairs (-4 VGPR) to pay for the +3 idx registers.
// launch_bounds (512,4) REQUIRED: 64-VGPR cap (r10: 72 VGPR -> occ 42->23%).
#define TILE_E 64

__global__ __launch_bounds__(512, 4) void edge_mlp11(
    const __bf16* __restrict__ xb,
    const float*  __restrict__ ea,       // [E,32] f32
    const __bf16* __restrict__ W1b,      // [128,160]
    const float*  __restrict__ b1,
    const __bf16* __restrict__ W2b,      // [128,128]
    const float*  __restrict__ b2,
    const int4*   __restrict__ einfo,    // [E] slot -> {src,dst,e,0}
    float* __restrict__ agg,             // [N,128] f32, zeroed
    int ntiles)
{
  __shared__ __bf16 Als[TILE_E * 160];   // 20 KB; first 16KB reused as M
  __shared__ __bf16 H1[TILE_E * 128];    // 16 KB
  __shared__ int dstls[TILE_E];
  char* AB = (char*)Als;
  char* HB = (char*)H1;

  const int tid = threadIdx.x;
  const int w  = tid >> 6;
  const int l  = tid & 63;
  const int l4 = l >> 4;
  const int lm = l & 15;
  const int jb = w * 16;

  // weight fragments (A operand): row j = jb+lm, k = kt*32 + l4*8
  bf16x8 bw1[5], bw2[4];
  {
    const int jr = jb + lm;
#pragma unroll
    for (int kt = 0; kt < 5; ++kt)
      bw1[kt] = *reinterpret_cast<const bf16x8*>(W1b + (size_t)jr * 160 + kt * 32 + l4 * 8);
#pragma unroll
    for (int kt = 0; kt < 4; ++kt)
      bw2[kt] = *reinterpret_cast<const bf16x8*>(W2b + (size_t)jr * 128 + kt * 32 + l4 * 8);
  }
  // biases packed bf16 (rows j = jb + l4*4 + rr): 2 u32 each
  unsigned b1p0, b1p1, b2p0, b2p1;
  {
    const float* p1 = b1 + jb + l4 * 4;
    const float* p2 = b2 + jb + l4 * 4;
    b1p0 = pk2(p1[0], p1[1]); b1p1 = pk2(p1[2], p1[3]);
    b2p0 = pk2(p2[0], p2[1]); b2p1 = pk2(p2[2], p2[3]);
  }

  // staging thread mapping
  const int xslot = tid >> 4, xq = tid & 15;     // x: 2 chunks (slots xslot, xslot+32)
  const int aslot = tid >> 3, aq = tid & 7;      // ea: 1 float4

  // prefetch registers
  bf16x8 pxv0 = {}, pxv1 = {};
  float4 pea_ = {};
  int pdst_ = 0;
  int ps0 = 0, ps1 = 0, pe2 = 0;                 // idx regs (stage 1)

  auto PREFETCH_IDX = [&](int t) {
    int p0 = t * TILE_E;
    ps0 = einfo[p0 + xslot].x;
    ps1 = einfo[p0 + xslot + 32].x;
    pe2 = einfo[p0 + aslot].z;
    if (tid < TILE_E) pdst_ = einfo[p0 + tid].y;
  };
  auto PREFETCH_DATA = [&]() {
    pxv0 = *reinterpret_cast<const bf16x8*>(xb + (size_t)ps0 * ND + xq * 8);
    pxv1 = *reinterpret_cast<const bf16x8*>(xb + (size_t)ps1 * ND + xq * 8);
    pea_ = reinterpret_cast<const float4*>(ea)[(size_t)pe2 * 8 + aq];
  };

  // bijective XCD-chunked swizzle of block id (m204)
  int nwg = gridDim.x;
  int q = nwg >> 3, r = nwg & 7;
  int xcd = blockIdx.x & 7, pos = blockIdx.x >> 3;
  int swz = (xcd < r ? xcd * (q + 1) : r * (q + 1) + (xcd - r) * q) + pos;

  int tile = swz;
  if (tile < ntiles) { PREFETCH_IDX(tile); PREFETCH_DATA(); }

  for (; tile < ntiles; tile += gridDim.x) {
    bar_lds();   // A: prev flush's LDS reads done

    // ---- write staged regs -> LDS ----
    {
      int s_ = xslot;
      *reinterpret_cast<bf16x8*>(AB + s_ * 320 + ((xq ^ (s_ & 7)) << 4)) = pxv0;
      int s2 = xslot + 32;
      *reinterpret_cast<bf16x8*>(AB + s2 * 320 + ((xq ^ (s2 & 7)) << 4)) = pxv1;
    }
    {
      bf16x4 h;
      h[0] = (__bf16)pea_.x; h[1] = (__bf16)pea_.y;
      h[2] = (__bf16)pea_.z; h[3] = (__bf16)pea_.w;
      int pc = 16 + ((aq >> 1) ^ (aslot & 3));
      *reinterpret_cast<bf16x4*>(AB + aslot * 320 + (pc << 4) + ((aq & 1) << 3)) = h;
    }
    if (tid < TILE_E) dstls[tid] = pdst_;
    bar_lds();   // B: tile staged

    // ---- prefetch stage 1: einfo gathers (latency hides under L1) ----
    int nt = tile + gridDim.x;
    if (nt < ntiles) PREFETCH_IDX(nt);

    __builtin_amdgcn_s_setprio(1);
    // ---- layer 1: H1^T[j][slot] = silu(W1 . A^T) ----
#pragma unroll
    for (int et = 0; et < 4; ++et) {
      const int s_ = et * 16 + lm;
      const int sw = s_ & 7;
      f32x4 acc = { __uint_as_float(b1p0 << 16), __uint_as_float(b1p0 & 0xffff0000u),
                    __uint_as_float(b1p1 << 16), __uint_as_float(b1p1 & 0xffff0000u) };
#pragma unroll
      for (int kt = 0; kt < 4; ++kt) {
        bf16x8 bfrag = *reinterpret_cast<const bf16x8*>(AB + s_ * 320 + (((kt * 4 + l4) ^ sw) << 4));
        acc = mfma_bf16(bw1[kt], bfrag, acc);
      }
      {
        bf16x8 bfrag = *reinterpret_cast<const bf16x8*>(AB + s_ * 320 + ((16 + (l4 ^ (s_ & 3))) << 4));
        acc = mfma_bf16(bw1[4], bfrag, acc);
      }
      bf16x4 h0;
#pragma unroll
      for (int rr = 0; rr < 4; ++rr)
        h0[rr] = (__bf16)fast_silu(acc[rr]);
      int c0 = w * 2 + (l4 >> 1);
      int inner = (l4 & 1) << 3;
      *reinterpret_cast<bf16x4*>(HB + s_ * 256 + ((c0 ^ sw) << 4) + inner) = h0;
    }
    bar_lds();   // C: H1 visible

    // ---- prefetch stage 2: dependent x/ea gathers (hide under L2+flush) ----
    if (nt < ntiles) PREFETCH_DATA();

    // ---- layer 2: M^T[j][slot] = silu(W2 . H1^T) -> M tile in A region ----
#pragma unroll
    for (int et = 0; et < 4; ++et) {
      const int s_ = et * 16 + lm;
      const int sw = s_ & 7;
      f32x4 acc = { __uint_as_float(b2p0 << 16), __uint_as_float(b2p0 & 0xffff0000u),
                    __uint_as_float(b2p1 << 16), __uint_as_float(b2p1 & 0xffff0000u) };
#pragma unroll
      for (int kt = 0; kt < 4; ++kt) {
        bf16x8 bfrag = *reinterpret_cast<const bf16x8*>(HB + s_ * 256 + (((kt * 4 + l4) ^ sw) << 4));
        acc = mfma_bf16(bw2[kt], bfrag, acc);
      }
      bf16x4 m0;
#pragma unroll
      for (int rr = 0; rr < 4; ++rr)
        m0[rr] = (__bf16)fast_silu(acc[rr]);
      int c0 = w * 2 + (l4 >> 1);
      int inner = (l4 & 1) << 3;
      *reinterpret_cast<bf16x4*>(AB + s_ * 256 + ((c0 ^ sw) << 4) + inner) = m0;
    }
    __builtin_amdgcn_s_setprio(0);
    bar_lds();   // D: M visible

    // ---- segmented flush: waves 0-3, 16-slot groups, b32 col-pairs ----
    if (w < 4) {
      const int base = w * 16;
      int myd = dstls[base + (l & 15)];
      float a0 = 0.f, a1 = 0.f;
      int cur = __builtin_amdgcn_readlane(myd, 0);
#pragma unroll
      for (int i = 0; i < 16; ++i) {
        int nd = __builtin_amdgcn_readlane(myd, i);
        if (nd != cur) {
          atomicAdd(agg + (size_t)cur * HID + l * 2, a0);
          atomicAdd(agg + (size_t)cur * HID + l * 2 + 1, a1);
          a0 = 0.f; a1 = 0.f; cur = nd;
        }
        int ss = base + i;
        uint32_t u = *reinterpret_cast<const uint32_t*>(
            AB + ss * 256 + (((l >> 2) ^ (ss & 7)) << 4) + ((l & 3) << 2));
        a0 += __uint_as_float(u << 16);
        a1 += __uint_as_float(u & 0xffff0000u);
      }
      atomicAdd(agg + (size_t)cur * HID + l * 2, a0);
      atomicAdd(agg + (size_t)cur * HID + l * 2 + 1, a1);
    }
  }
}

// ================= GRU (weights-as-A, transposed, grid-strided) =============
__global__ __launch_bounds__(512) void gru3(
    const float*  __restrict__ agg,      // [N,128] f32
    const __bf16* __restrict__ xb,
    const float*  __restrict__ x,
    const __bf16* __restrict__ Wih, const float* __restrict__ bih,  // [384,128]
    const __bf16* __restrict__ Whh, const float* __restrict__ bhh,
    float* __restrict__ out, int N, int ntilesN)
{
  const int tid = threadIdx.x;
  const int w = tid >> 6, l = tid & 63;
  const int l4 = l >> 4, lm = l & 15;
  const int jb = w * 16;
  const int jr = jb + lm, jz = jr + 128, jn = jr + 256;

  bf16x8 WiR[4], WhR[4], WiZ[4], WhZ[4], WiN[4], WhN[4];
#pragma unroll
  for (int kt = 0; kt < 4; ++kt) {
    int ko = kt * 32 + l4 * 8;
    WiR[kt] = *reinterpret_cast<const bf16x8*>(Wih + (size_t)jr * ND + ko);
    WhR[kt] = *reinterpret_cast<const bf16x8*>(Whh + (size_t)jr * ND + ko);
    WiZ[kt] = *reinterpret_cast<const bf16x8*>(Wih + (size_t)jz * ND + ko);
    WhZ[kt] = *reinterpret_cast<const bf16x8*>(Whh + (size_t)jz * ND + ko);
    WiN[kt] = *reinterpret_cast<const bf16x8*>(Wih + (size_t)jn * ND + ko);
    WhN[kt] = *reinterpret_cast<const bf16x8*>(Whh + (size_t)jn * ND + ko);
  }
  float4 birv, bizv, binv, bhnv;
  {
    int j0 = jb + l4 * 4;
    float4 a = *reinterpret_cast<const float4*>(bih + j0);
    float4 b = *reinterpret_cast<const float4*>(bhh + j0);
    birv = make_float4(a.x + b.x, a.y + b.y, a.z + b.z, a.w + b.w);
    a = *reinterpret_cast<const float4*>(bih + 128 + j0);
    b = *reinterpret_cast<const float4*>(bhh + 128 + j0);
    bizv = make_float4(a.x + b.x, a.y + b.y, a.z + b.z, a.w + b.w);
    binv = *reinterpret_cast<const float4*>(bih + 256 + j0);
    bhnv = *reinterpret_cast<const float4*>(bhh + 256 + j0);
  }

  for (int bt = blockIdx.x; bt < ntilesN; bt += gridDim.x) {
    const int n0 = bt * 64;
#pragma unroll
    for (int rt = 0; rt < 4; ++rt) {
      const int node = n0 + rt * 16 + lm;
      const bool ok = node < N;
      bf16x8 aA[4], aX[4];
#pragma unroll
      for (int kt = 0; kt < 4; ++kt) {
        int ko = kt * 32 + l4 * 8;
        bf16x8 z8 = {};
        if (ok) {
          float4 a0 = *reinterpret_cast<const float4*>(agg + (size_t)node * ND + ko);
          float4 a1 = *reinterpret_cast<const float4*>(agg + (size_t)node * ND + ko + 4);
          bf16x8 v;
          v[0] = (__bf16)a0.x; v[1] = (__bf16)a0.y; v[2] = (__bf16)a0.z; v[3] = (__bf16)a0.w;
          v[4] = (__bf16)a1.x; v[5] = (__bf16)a1.y; v[6] = (__bf16)a1.z; v[7] = (__bf16)a1.w;
          aA[kt] = v;
          aX[kt] = *reinterpret_cast<const bf16x8*>(xb + (size_t)node * ND + ko);
        } else {
          aA[kt] = z8;
          aX[kt] = z8;
        }
      }
      f32x4 aR = {0.f,0.f,0.f,0.f}, aZ = {0.f,0.f,0.f,0.f};
      f32x4 ai = {0.f,0.f,0.f,0.f}, ah = {0.f,0.f,0.f,0.f};
#pragma unroll
      for (int kt = 0; kt < 4; ++kt) {
        aR = mfma_bf16(WiR[kt], aA[kt], aR);
        aR = mfma_bf16(WhR[kt], aX[kt], aR);
        aZ = mfma_bf16(WiZ[kt], aA[kt], aZ);
        aZ = mfma_bf16(WhZ[kt], aX[kt], aZ);
        ai = mfma_bf16(WiN[kt], aA[kt], ai);
        ah = mfma_bf16(WhN[kt], aX[kt], ah);
      }
      if (ok) {
        float4 xv = *reinterpret_cast<const float4*>(x + (size_t)node * ND + jb + l4 * 4);
        float4 ov;
#pragma unroll
        for (int rr = 0; rr < 4; ++rr) {
          float r = fast_sigmoid(aR[rr] + (&birv.x)[rr]);
          float z = fast_sigmoid(aZ[rr] + (&bizv.x)[rr]);
          float n = fast_tanh(ai[rr] + (&binv.x)[rr] + r * (ah[rr] + (&bhnv.x)[rr]));
          (&ov.x)[rr] = (1.f - z) * n + z * (&xv.x)[rr];
        }
        *reinterpret_cast<float4*>(out + (size_t)node * ND + jb + l4 * 4) = ov;
      }
    }
  }
}

extern "C" void kernel_launch(void* const* d_in, const int* in_sizes, int n_in,
                              void* d_out, int out_size, void* d_ws, size_t ws_size,
                              hipStream_t stream) {
  const float* x   = (const float*)d_in[0];
  const int*   ei  = (const int*)d_in[1];
  const float* ea  = (const float*)d_in[2];
  const float* W1  = (const float*)d_in[3];
  const float* b1  = (const float*)d_in[4];
  const float* W2  = (const float*)d_in[5];
  const float* b2  = (const float*)d_in[6];
  const float* Wih = (const float*)d_in[7];
  const float* bih = (const float*)d_in[8];
  const float* Whh = (const float*)d_in[9];
  const float* bhh = (const float*)d_in[10];
  float* out = (float*)d_out;
  const int N = in_sizes[0] / ND;       // 50000
  const int E = in_sizes[1] / 2;        // 800000

  const int nb = (N + 255) / 256;
  const int nC = nb * 256;

  char* ws = (char*)d_ws;
  size_t off = 0;
  auto alloc = [&](size_t bytes) -> void* {
    void* p = ws + off;
    off += (bytes + 255) & ~(size_t)255;
    return p;
  };
  __bf16* xb      = (__bf16*)alloc((size_t)N * ND * 2);
  __bf16* W1b     = (__bf16*)alloc(128 * 160 * 2);
  __bf16* W2b     = (__bf16*)alloc(128 * 128 * 2);
  __bf16* Wihb    = (__bf16*)alloc(384 * 128 * 2);
  __bf16* Whhb    = (__bf16*)alloc(384 * 128 * 2);
  int*    counts  = (int*)alloc((size_t)nC * 4);
  int*    cursor  = (int*)alloc((size_t)nC * 4);
  int*    bsum    = (int*)alloc(256 * 4);
  int4*   einfo   = (int4*)alloc((size_t)E * 16);
  float*  agg     = (float*)alloc((size_t)N * ND * 4);
  (void)ws_size;

  const int* srcp = ei;
  const int* dstp = ei + E;

  const int n8_x = N * ND / 8, n8_1 = 128 * 160 / 8, n8_2 = 128 * 128 / 8, n8_g = 384 * 128 / 8;
  int c1 = n8_x, c2 = c1 + n8_1, c3 = c2 + n8_2, c4 = c3 + n8_g, c5 = c4 + n8_g;
  int aggz = N * ND / 8;
  int cntz = nC / 8;
  int prep_total = c5 + aggz + cntz;
  k_prep<<<(prep_total + 255) / 256, 256, 0, stream>>>(
      x, xb, c1, W1, W1b, c2, W2, W2b, c3, Wih, Wihb, c4, Whh, Whhb, c5,
      agg, aggz, counts, cntz);

  k_hist<<<(E + 255) / 256, 256, 0, stream>>>(dstp, counts, E);
  k_blocksum<<<nb, 256, 0, stream>>>(counts, bsum);
  k_scan_write<<<nb, 256, 0, stream>>>(counts, bsum, cursor, nb);
  k_perm<<<(E + 255) / 256, 256, 0, stream>>>(srcp, dstp, cursor, einfo, E);

  const int ntiles = E / TILE_E;   // 12500
  edge_mlp11<<<2500, 512, 0, stream>>>(xb, ea, W1b, b1, W2b, b2,
                                       einfo, agg, ntiles);

  const int ntilesN = (N + 63) / 64;
  gru3<<<256, 512, 0, stream>>>(agg, xb, x, Wihb, bih, Whhb, bhh, out, N, ntilesN);
}

// Round 17
// 323.870 us; speedup vs baseline: 1.0761x; 1.0023x over previous
//
#include <hip/hip_runtime.h>
#include <hip/hip_bf16.h>
#include <cstdint>

typedef __bf16 bf16x8 __attribute__((ext_vector_type(8)));
typedef __bf16 bf16x4 __attribute__((ext_vector_type(4)));
typedef float  f32x4  __attribute__((ext_vector_type(4)));

#define ND 128
#define HID 128

__device__ __forceinline__ f32x4 mfma_bf16(bf16x8 a, bf16x8 b, f32x4 c) {
  return __builtin_amdgcn_mfma_f32_16x16x32_bf16(a, b, c, 0, 0, 0);
}
__device__ __forceinline__ float fast_sigmoid(float x) {
  return __fdividef(1.f, 1.f + __expf(-x));
}
__device__ __forceinline__ float fast_silu(float x) {
  return __fdividef(x, 1.f + __expf(-x));
}
__device__ __forceinline__ float fast_tanh(float x) {
  float cx = fminf(fmaxf(x, -15.f), 15.f);
  float e = __expf(2.f * cx);
  return __fdividef(e - 1.f, e + 1.f);
}

// LDS-only barrier: drains lgkmcnt, leaves vmem (prefetch/atomics) in flight.
__device__ __forceinline__ void bar_lds() {
  asm volatile("s_waitcnt lgkmcnt(0)\n\ts_barrier" ::: "memory");
  __builtin_amdgcn_sched_barrier(0);
}

// pack two f32 into a u32 of 2 bf16 (truncation; r6-proven for biases)
__device__ __forceinline__ unsigned pk2(float a, float b) {
  return (__builtin_bit_cast(unsigned, a) >> 16) |
         (__builtin_bit_cast(unsigned, b) & 0xffff0000u);
}

// ---- prep: zero agg + zero counts + f32->bf16 cvt over 5 segments ----
__global__ void k_prep(const float* __restrict__ s0, __bf16* __restrict__ d0, int c1,
                       const float* __restrict__ s1, __bf16* __restrict__ d1, int c2,
                       const float* __restrict__ s2, __bf16* __restrict__ d2, int c3,
                       const float* __restrict__ s3, __bf16* __restrict__ d3, int c4,
                       const float* __restrict__ s4, __bf16* __restrict__ d4, int c5,
                       float* __restrict__ agg, int aggz,
                       int* __restrict__ counts, int cntz) {
  int i = blockIdx.x * blockDim.x + threadIdx.x;
  if (i < c5) {
    const float* s; __bf16* d; int j;
    if (i < c1)      { s = s0; d = d0; j = i; }
    else if (i < c2) { s = s1; d = d1; j = i - c1; }
    else if (i < c3) { s = s2; d = d2; j = i - c2; }
    else if (i < c4) { s = s3; d = d3; j = i - c3; }
    else             { s = s4; d = d4; j = i - c4; }
    const float4* sp = reinterpret_cast<const float4*>(s) + (size_t)j * 2;
    float4 a = sp[0], b = sp[1];
    bf16x8 v;
    v[0] = (__bf16)a.x; v[1] = (__bf16)a.y; v[2] = (__bf16)a.z; v[3] = (__bf16)a.w;
    v[4] = (__bf16)b.x; v[5] = (__bf16)b.y; v[6] = (__bf16)b.z; v[7] = (__bf16)b.w;
    reinterpret_cast<bf16x8*>(d)[j] = v;
    return;
  }
  int k = i - c5;
  if (k < aggz) {
    float4 z = make_float4(0.f, 0.f, 0.f, 0.f);
    float4* p = reinterpret_cast<float4*>(agg) + (size_t)k * 2;
    p[0] = z; p[1] = z;
    return;
  }
  k -= aggz;
  if (k < cntz) {
    int4 z = make_int4(0, 0, 0, 0);
    int4* p = reinterpret_cast<int4*>(counts) + (size_t)k * 2;
    p[0] = z; p[1] = z;
  }
}

// ================= sort machinery =================
__global__ void k_hist(const int* __restrict__ dst, int* __restrict__ counts, int E) {
  int e = blockIdx.x * 256 + threadIdx.x;
  if (e < E) atomicAdd(&counts[dst[e]], 1);
}

__global__ void k_blocksum(const int* __restrict__ counts, int* __restrict__ bsum) {
  __shared__ int sd[256];
  int t = threadIdx.x;
  sd[t] = counts[blockIdx.x * 256 + t];
  __syncthreads();
  for (int d = 128; d > 0; d >>= 1) { if (t < d) sd[t] += sd[t + d]; __syncthreads(); }
  if (!t) bsum[blockIdx.x] = sd[0];
}

// fused: recompute bsum exclusive prefix per block, then scan local counts
__global__ void k_scan_write(const int* __restrict__ counts, const int* __restrict__ bsum,
                             int* __restrict__ cursor, int nb) {
  __shared__ int sd[256];
  int t = threadIdx.x, b = blockIdx.x;
  int v = (t < nb) ? bsum[t] : 0;
  sd[t] = v;
  __syncthreads();
  for (int d = 1; d < 256; d <<= 1) {
    int u = (t >= d) ? sd[t - d] : 0;
    __syncthreads();
    sd[t] += u;
    __syncthreads();
  }
  int bexcl = (b == 0) ? 0 : sd[b - 1];
  __syncthreads();
  int i = b * 256 + t;
  int c = counts[i];
  sd[t] = c;
  __syncthreads();
  for (int d = 1; d < 256; d <<= 1) {
    int u = (t >= d) ? sd[t - d] : 0;
    __syncthreads();
    sd[t] += u;
    __syncthreads();
  }
  cursor[i] = bexcl + sd[t] - c;   // exclusive prefix
}

// one scattered 16B store per edge: {src, dst, e, 0} at sorted position
__global__ void k_perm(const int* __restrict__ src, const int* __restrict__ dst,
                       int* __restrict__ cursor, int4* __restrict__ einfo, int E) {
  int e = blockIdx.x * 256 + threadIdx.x;
  if (e < E) {
    int d = dst[e];
    int p = atomicAdd(&cursor[d], 1);
    einfo[p] = make_int4(src[e], d, e, 0);
  }
}

// ================= fused edge MLP + aggregate (split prefetch, 8w flush) =====
// r16 body (split prefetch, packed biases). NEW: flush repartitioned to all
// 8 waves x 8-slot groups (halves the serial segmented scan; ~1.6x atomic
// segments, +~47MB WRITE hidden behind compute).
// launch_bounds (512,4) REQUIRED: 64-VGPR cap (r10: 72 VGPR -> occ 42->23%).
#define TILE_E 64

__global__ __launch_bounds__(512, 4) void edge_mlp12(
    const __bf16* __restrict__ xb,
    const float*  __restrict__ ea,       // [E,32] f32
    const __bf16* __restrict__ W1b,      // [128,160]
    const float*  __restrict__ b1,
    const __bf16* __restrict__ W2b,      // [128,128]
    const float*  __restrict__ b2,
    const int4*   __restrict__ einfo,    // [E] slot -> {src,dst,e,0}
    float* __restrict__ agg,             // [N,128] f32, zeroed
    int ntiles)
{
  __shared__ __bf16 Als[TILE_E * 160];   // 20 KB; first 16KB reused as M
  __shared__ __bf16 H1[TILE_E * 128];    // 16 KB
  __shared__ int dstls[TILE_E];
  char* AB = (char*)Als;
  char* HB = (char*)H1;

  const int tid = threadIdx.x;
  const int w  = tid >> 6;
  const int l  = tid & 63;
  const int l4 = l >> 4;
  const int lm = l & 15;
  const int jb = w * 16;

  // weight fragments (A operand): row j = jb+lm, k = kt*32 + l4*8
  bf16x8 bw1[5], bw2[4];
  {
    const int jr = jb + lm;
#pragma unroll
    for (int kt = 0; kt < 5; ++kt)
      bw1[kt] = *reinterpret_cast<const bf16x8*>(W1b + (size_t)jr * 160 + kt * 32 + l4 * 8);
#pragma unroll
    for (int kt = 0; kt < 4; ++kt)
      bw2[kt] = *reinterpret_cast<const bf16x8*>(W2b + (size_t)jr * 128 + kt * 32 + l4 * 8);
  }
  // biases packed bf16 (rows j = jb + l4*4 + rr): 2 u32 each
  unsigned b1p0, b1p1, b2p0, b2p1;
  {
    const float* p1 = b1 + jb + l4 * 4;
    const float* p2 = b2 + jb + l4 * 4;
    b1p0 = pk2(p1[0], p1[1]); b1p1 = pk2(p1[2], p1[3]);
    b2p0 = pk2(p2[0], p2[1]); b2p1 = pk2(p2[2], p2[3]);
  }

  // staging thread mapping
  const int xslot = tid >> 4, xq = tid & 15;     // x: 2 chunks (slots xslot, xslot+32)
  const int aslot = tid >> 3, aq = tid & 7;      // ea: 1 float4

  // prefetch registers
  bf16x8 pxv0 = {}, pxv1 = {};
  float4 pea_ = {};
  int pdst_ = 0;
  int ps0 = 0, ps1 = 0, pe2 = 0;                 // idx regs (stage 1)

  auto PREFETCH_IDX = [&](int t) {
    int p0 = t * TILE_E;
    ps0 = einfo[p0 + xslot].x;
    ps1 = einfo[p0 + xslot + 32].x;
    pe2 = einfo[p0 + aslot].z;
    if (tid < TILE_E) pdst_ = einfo[p0 + tid].y;
  };
  auto PREFETCH_DATA = [&]() {
    pxv0 = *reinterpret_cast<const bf16x8*>(xb + (size_t)ps0 * ND + xq * 8);
    pxv1 = *reinterpret_cast<const bf16x8*>(xb + (size_t)ps1 * ND + xq * 8);
    pea_ = reinterpret_cast<const float4*>(ea)[(size_t)pe2 * 8 + aq];
  };

  // bijective XCD-chunked swizzle of block id (m204)
  int nwg = gridDim.x;
  int q = nwg >> 3, r = nwg & 7;
  int xcd = blockIdx.x & 7, pos = blockIdx.x >> 3;
  int swz = (xcd < r ? xcd * (q + 1) : r * (q + 1) + (xcd - r) * q) + pos;

  int tile = swz;
  if (tile < ntiles) { PREFETCH_IDX(tile); PREFETCH_DATA(); }

  for (; tile < ntiles; tile += gridDim.x) {
    bar_lds();   // A: prev flush's LDS reads done

    // ---- write staged regs -> LDS ----
    {
      int s_ = xslot;
      *reinterpret_cast<bf16x8*>(AB + s_ * 320 + ((xq ^ (s_ & 7)) << 4)) = pxv0;
      int s2 = xslot + 32;
      *reinterpret_cast<bf16x8*>(AB + s2 * 320 + ((xq ^ (s2 & 7)) << 4)) = pxv1;
    }
    {
      bf16x4 h;
      h[0] = (__bf16)pea_.x; h[1] = (__bf16)pea_.y;
      h[2] = (__bf16)pea_.z; h[3] = (__bf16)pea_.w;
      int pc = 16 + ((aq >> 1) ^ (aslot & 3));
      *reinterpret_cast<bf16x4*>(AB + aslot * 320 + (pc << 4) + ((aq & 1) << 3)) = h;
    }
    if (tid < TILE_E) dstls[tid] = pdst_;
    bar_lds();   // B: tile staged

    // ---- prefetch stage 1: einfo gathers (latency hides under L1) ----
    int nt = tile + gridDim.x;
    if (nt < ntiles) PREFETCH_IDX(nt);

    __builtin_amdgcn_s_setprio(1);
    // ---- layer 1: H1^T[j][slot] = silu(W1 . A^T) ----
#pragma unroll
    for (int et = 0; et < 4; ++et) {
      const int s_ = et * 16 + lm;
      const int sw = s_ & 7;
      f32x4 acc = { __uint_as_float(b1p0 << 16), __uint_as_float(b1p0 & 0xffff0000u),
                    __uint_as_float(b1p1 << 16), __uint_as_float(b1p1 & 0xffff0000u) };
#pragma unroll
      for (int kt = 0; kt < 4; ++kt) {
        bf16x8 bfrag = *reinterpret_cast<const bf16x8*>(AB + s_ * 320 + (((kt * 4 + l4) ^ sw) << 4));
        acc = mfma_bf16(bw1[kt], bfrag, acc);
      }
      {
        bf16x8 bfrag = *reinterpret_cast<const bf16x8*>(AB + s_ * 320 + ((16 + (l4 ^ (s_ & 3))) << 4));
        acc = mfma_bf16(bw1[4], bfrag, acc);
      }
      bf16x4 h0;
#pragma unroll
      for (int rr = 0; rr < 4; ++rr)
        h0[rr] = (__bf16)fast_silu(acc[rr]);
      int c0 = w * 2 + (l4 >> 1);
      int inner = (l4 & 1) << 3;
      *reinterpret_cast<bf16x4*>(HB + s_ * 256 + ((c0 ^ sw) << 4) + inner) = h0;
    }
    bar_lds();   // C: H1 visible

    // ---- prefetch stage 2: dependent x/ea gathers (hide under L2+flush) ----
    if (nt < ntiles) PREFETCH_DATA();

    // ---- layer 2: M^T[j][slot] = silu(W2 . H1^T) -> M tile in A region ----
#pragma unroll
    for (int et = 0; et < 4; ++et) {
      const int s_ = et * 16 + lm;
      const int sw = s_ & 7;
      f32x4 acc = { __uint_as_float(b2p0 << 16), __uint_as_float(b2p0 & 0xffff0000u),
                    __uint_as_float(b2p1 << 16), __uint_as_float(b2p1 & 0xffff0000u) };
#pragma unroll
      for (int kt = 0; kt < 4; ++kt) {
        bf16x8 bfrag = *reinterpret_cast<const bf16x8*>(HB + s_ * 256 + (((kt * 4 + l4) ^ sw) << 4));
        acc = mfma_bf16(bw2[kt], bfrag, acc);
      }
      bf16x4 m0;
#pragma unroll
      for (int rr = 0; rr < 4; ++rr)
        m0[rr] = (__bf16)fast_silu(acc[rr]);
      int c0 = w * 2 + (l4 >> 1);
      int inner = (l4 & 1) << 3;
      *reinterpret_cast<bf16x4*>(AB + s_ * 256 + ((c0 ^ sw) << 4) + inner) = m0;
    }
    __builtin_amdgcn_s_setprio(0);
    bar_lds();   // D: M visible

    // ---- segmented flush: ALL 8 waves, 8-slot groups, b32 col-pairs ----
    {
      const int base = w * 8;
      int myd = dstls[base + (l & 7)];
      float a0 = 0.f, a1 = 0.f;
      int cur = __builtin_amdgcn_readlane(myd, 0);
#pragma unroll
      for (int i = 0; i < 8; ++i) {
        int nd = __builtin_amdgcn_readlane(myd, i);
        if (nd != cur) {
          atomicAdd(agg + (size_t)cur * HID + l * 2, a0);
          atomicAdd(agg + (size_t)cur * HID + l * 2 + 1, a1);
          a0 = 0.f; a1 = 0.f; cur = nd;
        }
        int ss = base + i;
        uint32_t u = *reinterpret_cast<const uint32_t*>(
            AB + ss * 256 + (((l >> 2) ^ (ss & 7)) << 4) + ((l & 3) << 2));
        a0 += __uint_as_float(u << 16);
        a1 += __uint_as_float(u & 0xffff0000u);
      }
      atomicAdd(agg + (size_t)cur * HID + l * 2, a0);
      atomicAdd(agg + (size_t)cur * HID + l * 2 + 1, a1);
    }
  }
}

// ================= GRU (weights-as-A, transposed, grid-strided) =============
__global__ __launch_bounds__(512) void gru3(
    const float*  __restrict__ agg,      // [N,128] f32
    const __bf16* __restrict__ xb,
    const float*  __restrict__ x,
    const __bf16* __restrict__ Wih, const float* __restrict__ bih,  // [384,128]
    const __bf16* __restrict__ Whh, const float* __restrict__ bhh,
    float* __restrict__ out, int N, int ntilesN)
{
  const int tid = threadIdx.x;
  const int w = tid >> 6, l = tid & 63;
  const int l4 = l >> 4, lm = l & 15;
  const int jb = w * 16;
  const int jr = jb + lm, jz = jr + 128, jn = jr + 256;

  bf16x8 WiR[4], WhR[4], WiZ[4], WhZ[4], WiN[4], WhN[4];
#pragma unroll
  for (int kt = 0; kt < 4; ++kt) {
    int ko = kt * 32 + l4 * 8;
    WiR[kt] = *reinterpret_cast<const bf16x8*>(Wih + (size_t)jr * ND + ko);
    WhR[kt] = *reinterpret_cast<const bf16x8*>(Whh + (size_t)jr * ND + ko);
    WiZ[kt] = *reinterpret_cast<const bf16x8*>(Wih + (size_t)jz * ND + ko);
    WhZ[kt] = *reinterpret_cast<const bf16x8*>(Whh + (size_t)jz * ND + ko);
    WiN[kt] = *reinterpret_cast<const bf16x8*>(Wih + (size_t)jn * ND + ko);
    WhN[kt] = *reinterpret_cast<const bf16x8*>(Whh + (size_t)jn * ND + ko);
  }
  float4 birv, bizv, binv, bhnv;
  {
    int j0 = jb + l4 * 4;
    float4 a = *reinterpret_cast<const float4*>(bih + j0);
    float4 b = *reinterpret_cast<const float4*>(bhh + j0);
    birv = make_float4(a.x + b.x, a.y + b.y, a.z + b.z, a.w + b.w);
    a = *reinterpret_cast<const float4*>(bih + 128 + j0);
    b = *reinterpret_cast<const float4*>(bhh + 128 + j0);
    bizv = make_float4(a.x + b.x, a.y + b.y, a.z + b.z, a.w + b.w);
    binv = *reinterpret_cast<const float4*>(bih + 256 + j0);
    bhnv = *reinterpret_cast<const float4*>(bhh + 256 + j0);
  }

  for (int bt = blockIdx.x; bt < ntilesN; bt += gridDim.x) {
    const int n0 = bt * 64;
#pragma unroll
    for (int rt = 0; rt < 4; ++rt) {
      const int node = n0 + rt * 16 + lm;
      const bool ok = node < N;
      bf16x8 aA[4], aX[4];
#pragma unroll
      for (int kt = 0; kt < 4; ++kt) {
        int ko = kt * 32 + l4 * 8;
        bf16x8 z8 = {};
        if (ok) {
          float4 a0 = *reinterpret_cast<const float4*>(agg + (size_t)node * ND + ko);
          float4 a1 = *reinterpret_cast<const float4*>(agg + (size_t)node * ND + ko + 4);
          bf16x8 v;
          v[0] = (__bf16)a0.x; v[1] = (__bf16)a0.y; v[2] = (__bf16)a0.z; v[3] = (__bf16)a0.w;
          v[4] = (__bf16)a1.x; v[5] = (__bf16)a1.y; v[6] = (__bf16)a1.z; v[7] = (__bf16)a1.w;
          aA[kt] = v;
          aX[kt] = *reinterpret_cast<const bf16x8*>(xb + (size_t)node * ND + ko);
        } else {
          aA[kt] = z8;
          aX[kt] = z8;
        }
      }
      f32x4 aR = {0.f,0.f,0.f,0.f}, aZ = {0.f,0.f,0.f,0.f};
      f32x4 ai = {0.f,0.f,0.f,0.f}, ah = {0.f,0.f,0.f,0.f};
#pragma unroll
      for (int kt = 0; kt < 4; ++kt) {
        aR = mfma_bf16(WiR[kt], aA[kt], aR);
        aR = mfma_bf16(WhR[kt], aX[kt], aR);
        aZ = mfma_bf16(WiZ[kt], aA[kt], aZ);
        aZ = mfma_bf16(WhZ[kt], aX[kt], aZ);
        ai = mfma_bf16(WiN[kt], aA[kt], ai);
        ah = mfma_bf16(WhN[kt], aX[kt], ah);
      }
      if (ok) {
        float4 xv = *reinterpret_cast<const float4*>(x + (size_t)node * ND + jb + l4 * 4);
        float4 ov;
#pragma unroll
        for (int rr = 0; rr < 4; ++rr) {
          float r = fast_sigmoid(aR[rr] + (&birv.x)[rr]);
          float z = fast_sigmoid(aZ[rr] + (&bizv.x)[rr]);
          float n = fast_tanh(ai[rr] + (&binv.x)[rr] + r * (ah[rr] + (&bhnv.x)[rr]));
          (&ov.x)[rr] = (1.f - z) * n + z * (&xv.x)[rr];
        }
        *reinterpret_cast<float4*>(out + (size_t)node * ND + jb + l4 * 4) = ov;
      }
    }
  }
}

extern "C" void kernel_launch(void* const* d_in, const int* in_sizes, int n_in,
                              void* d_out, int out_size, void* d_ws, size_t ws_size,
                              hipStream_t stream) {
  const float* x   = (const float*)d_in[0];
  const int*   ei  = (const int*)d_in[1];
  const float* ea  = (const float*)d_in[2];
  const float* W1  = (const float*)d_in[3];
  const float* b1  = (const float*)d_in[4];
  const float* W2  = (const float*)d_in[5];
  const float* b2  = (const float*)d_in[6];
  const float* Wih = (const float*)d_in[7];
  const float* bih = (const float*)d_in[8];
  const float* Whh = (const float*)d_in[9];
  const float* bhh = (const float*)d_in[10];
  float* out = (float*)d_out;
  const int N = in_sizes[0] / ND;       // 50000
  const int E = in_sizes[1] / 2;        // 800000

  const int nb = (N + 255) / 256;
  const int nC = nb * 256;

  char* ws = (char*)d_ws;
  size_t off = 0;
  auto alloc = [&](size_t bytes) -> void* {
    void* p = ws + off;
    off += (bytes + 255) & ~(size_t)255;
    return p;
  };
  __bf16* xb      = (__bf16*)alloc((size_t)N * ND * 2);
  __bf16* W1b     = (__bf16*)alloc(128 * 160 * 2);
  __bf16* W2b     = (__bf16*)alloc(128 * 128 * 2);
  __bf16* Wihb    = (__bf16*)alloc(384 * 128 * 2);
  __bf16* Whhb    = (__bf16*)alloc(384 * 128 * 2);
  int*    counts  = (int*)alloc((size_t)nC * 4);
  int*    cursor  = (int*)alloc((size_t)nC * 4);
  int*    bsum    = (int*)alloc(256 * 4);
  int4*   einfo   = (int4*)alloc((size_t)E * 16);
  float*  agg     = (float*)alloc((size_t)N * ND * 4);
  (void)ws_size;

  const int* srcp = ei;
  const int* dstp = ei + E;

  const int n8_x = N * ND / 8, n8_1 = 128 * 160 / 8, n8_2 = 128 * 128 / 8, n8_g = 384 * 128 / 8;
  int c1 = n8_x, c2 = c1 + n8_1, c3 = c2 + n8_2, c4 = c3 + n8_g, c5 = c4 + n8_g;
  int aggz = N * ND / 8;
  int cntz = nC / 8;
  int prep_total = c5 + aggz + cntz;
  k_prep<<<(prep_total + 255) / 256, 256, 0, stream>>>(
      x, xb, c1, W1, W1b, c2, W2, W2b, c3, Wih, Wihb, c4, Whh, Whhb, c5,
      agg, aggz, counts, cntz);

  k_hist<<<(E + 255) / 256, 256, 0, stream>>>(dstp, counts, E);
  k_blocksum<<<nb, 256, 0, stream>>>(counts, bsum);
  k_scan_write<<<nb, 256, 0, stream>>>(counts, bsum, cursor, nb);
  k_perm<<<(E + 255) / 256, 256, 0, stream>>>(srcp, dstp, cursor, einfo, E);

  const int ntiles = E / TILE_E;   // 12500
  edge_mlp12<<<2500, 512, 0, stream>>>(xb, ea, W1b, b1, W2b, b2,
                                       einfo, agg, ntiles);

  const int ntilesN = (N + 63) / 64;
  gru3<<<256, 512, 0, stream>>>(agg, xb, x, Wihb, bih, Whhb, bhh, out, N, ntilesN);
}